// Round 16
// baseline (1990.867 us; speedup 1.0000x reference)
//
#include <hip/hip_runtime.h>
#include <stdint.h>

#define H_DIM 128   // hidden width (fixed by weight shapes)
#define D_IN  64    // input feature dim (fixed by weight shapes)

typedef __attribute__((ext_vector_type(8))) short bf16x8;
typedef __attribute__((ext_vector_type(4))) float f32x4;

// ---------------- threefry2x32-20, bit-exact with JAX ----------------
__host__ __device__ __forceinline__ void tf2x32(uint32_t k0, uint32_t k1,
    uint32_t x0, uint32_t x1, uint32_t* o0, uint32_t* o1)
{
  uint32_t ks0 = k0, ks1 = k1, ks2 = k0 ^ k1 ^ 0x1BD11BDAu;
  x0 += ks0; x1 += ks1;
#define TFR(r) { x0 += x1; x1 = (x1 << (r)) | (x1 >> (32-(r))); x1 ^= x0; }
  TFR(13) TFR(15) TFR(26) TFR(6)   x0 += ks1; x1 += ks2 + 1u;
  TFR(17) TFR(29) TFR(16) TFR(24)  x0 += ks2; x1 += ks0 + 2u;
  TFR(13) TFR(15) TFR(26) TFR(6)   x0 += ks0; x1 += ks1 + 3u;
  TFR(17) TFR(29) TFR(16) TFR(24)  x0 += ks1; x1 += ks2 + 4u;
  TFR(13) TFR(15) TFR(26) TFR(6)   x0 += ks2; x1 += ks0 + 5u;
#undef TFR
  *o0 = x0; *o1 = x1;
}

__device__ __forceinline__ float bfu(unsigned short u){
  return __uint_as_float(((unsigned int)u) << 16);
}
__device__ __forceinline__ unsigned short f2bf(float f){  // RNE
  unsigned int u = __float_as_uint(f);
  u += 0x7fffu + ((u >> 16) & 1u);
  return (unsigned short)(u >> 16);
}

// LN + ReLU + partitionable-threefry dropout (xor-fold — verified R10)
__device__ __forceinline__ float ln_drop(float vraw, float mu, float inv,
    float g, float be, uint32_t k0, uint32_t k1, uint32_t j)
{
  float y = fmaxf(fmaf((vraw - mu)*inv, g, be), 0.f);
  uint32_t b0, b1;
  tf2x32(k0, k1, 0u, j, &b0, &b1);
  uint32_t bits = b0 ^ b1;
  float u = __uint_as_float((bits >> 9) | 0x3f800000u) - 1.0f;
  return (u < 0.8f) ? (y / 0.8f) : 0.f;
}

// bf16 transposed weight layout (ushort offsets): WtIn[128][64], WtC0[128][128], WtC1[128][128]
#define WT_IN  0
#define WT_C0  8192
#define WT_C1  24576
#define WT_TOT 40960

// ---- prep: zero cnt + counters, build bf16 transposed weights from f32 inputs ----
__global__ __launch_bounds__(256) void k_prep(int* __restrict__ cnt, int zb, int N,
    const float* __restrict__ W_in, const float* __restrict__ Wc,
    unsigned short* __restrict__ wt, int* __restrict__ counters)
{
  int b = blockIdx.x;
  if (b == 0 && threadIdx.x < 2) counters[threadIdx.x] = 0;
  if (b < zb){
    int i = b*256 + threadIdx.x;
    if (i < N) cnt[i] = 0;
  } else {
    int idx = (b - zb)*256 + threadIdx.x;
    if (idx >= WT_TOT) return;
    if (idx < WT_C0){                 // WtIn[n][k] = W_in[k][n]
      int n = idx >> 6, k = idx & 63;
      wt[idx] = f2bf(W_in[k*128 + n]);
    } else if (idx < WT_C1){          // WtC0[n][k] = Wc0[k][n]
      int r = idx - WT_C0; int n = r >> 7, k = r & 127;
      wt[idx] = f2bf(Wc[k*128 + n]);
    } else {                          // WtC1[n][k] = Wc1[k][n]
      int r = idx - WT_C1; int n = r >> 7, k = r & 127;
      wt[idx] = f2bf(Wc[16384 + k*128 + n]);
    }
  }
}

// ---------------- CSR build ----------------
__global__ __launch_bounds__(256) void k_count(const int* __restrict__ dst, int* __restrict__ cnt,
                                               int* __restrict__ perm, int E){
  int e = blockIdx.x*256 + threadIdx.x;
  if (e < E){
    int p = atomicAdd(&cnt[dst[e]], 1);
    perm[e] = p;
  }
}
__global__ __launch_bounds__(256) void k_scan1(const int* __restrict__ cnt, int* __restrict__ bsum, int N){
  int tid = threadIdx.x;
  int base = blockIdx.x*1024 + tid*4;
  int s = 0;
  #pragma unroll
  for (int j=0;j<4;++j){ int idx = base+j; if (idx < N) s += cnt[idx]; }
  __shared__ int sh[256];
  sh[tid] = s; __syncthreads();
  for (int o=128;o;o>>=1){ if (tid<o) sh[tid]+=sh[tid+o]; __syncthreads(); }
  if (tid==0) bsum[blockIdx.x] = sh[0];
}
// R16: parallel 128-thread scan (was a serial single-thread loop)
__global__ __launch_bounds__(128) void k_scan2(const int* __restrict__ bsum, int* __restrict__ boff,
                                               int nb, int* __restrict__ rowptr, int N){
  int tid = threadIdx.x;
  if (nb <= 128){
    int v = (tid < nb) ? bsum[tid] : 0;
    __shared__ int sh[128];
    sh[tid] = v; __syncthreads();
    for (int off=1; off<128; off<<=1){
      int t = 0; if (tid >= off) t = sh[tid-off];
      __syncthreads(); sh[tid] += t; __syncthreads();
    }
    if (tid < nb) boff[tid] = sh[tid] - v;
    if (tid == 127) rowptr[N] = sh[127];
  } else if (tid == 0){
    int run = 0;
    for (int b=0;b<nb;++b){ boff[b]=run; run += bsum[b]; }
    rowptr[N] = run;
  }
}
__global__ __launch_bounds__(256) void k_scan3(const int* __restrict__ cnt, const int* __restrict__ boff,
                                               int* __restrict__ rowptr, float* __restrict__ dinv, int N){
  int tid = threadIdx.x;
  int base = blockIdx.x*1024 + tid*4;
  int a[4]; int tsum = 0;
  #pragma unroll
  for (int j=0;j<4;++j){ int idx=base+j; a[j] = (idx < N) ? cnt[idx] : 0; tsum += a[j]; }
  __shared__ int sh[256];
  sh[tid] = tsum; __syncthreads();
  for (int off=1; off<256; off<<=1){
    int v = 0; if (tid>=off) v = sh[tid-off];
    __syncthreads(); sh[tid] += v; __syncthreads();
  }
  int run = boff[blockIdx.x] + (sh[tid] - tsum);
  #pragma unroll
  for (int j=0;j<4;++j){
    int idx=base+j;
    if (idx < N){
      rowptr[idx] = run;
      dinv[idx] = 1.0f / sqrtf(1.0f + (float)a[j]);
    }
    run += a[j];
  }
}
// CSR entry = (src byte-offset, fused coefficient dinv[src]*dinv[dst])
__global__ __launch_bounds__(256) void k_fill(const int* __restrict__ src, const int* __restrict__ dst,
                                              const int* __restrict__ rowptr, const int* __restrict__ perm,
                                              const float* __restrict__ dinv,
                                              int2* __restrict__ csr2, int E){
  int e = blockIdx.x*256 + threadIdx.x;
  if (e < E){
    int d = dst[e];
    int s = src[e];
    float cf = dinv[s]*dinv[d];
    csr2[rowptr[d] + perm[e]] = make_int2(s << 8, __float_as_int(cf));
  }
}

// ------- MFMA GEMM: C[M,128] = A[M,K] @ B[K,128], f32 accum; Bt transposed bf16.
// EXT: A is f32 (network input). LNDROP: A is pre-LN v (bf16); apply
// LN+ReLU+dropout inline on A-load (f2bf round-trip => bit-identical to the
// former separate ln_relu_drop pass). -------
template<int K, bool EXT, bool RELUBIAS, bool LNDROP>
__global__ __launch_bounds__(256) void gemm_mfma(const void* __restrict__ Av,
    const unsigned short* __restrict__ Bt, const float* __restrict__ bias,
    unsigned short* __restrict__ C, int M,
    const double* __restrict__ red, const float* __restrict__ gam,
    const float* __restrict__ bet, uint32_t k0f, uint32_t k1f, double tot)
{
  const int tid  = threadIdx.x;
  const int wid  = tid >> 6;
  const int lane = tid & 63;
  const int l15  = lane & 15;
  const int quad = lane >> 4;
  const int rowBase = blockIdx.x * 64;
  const int col0 = wid * 32;

  float mu = 0.f, inv = 0.f;
  if (LNDROP){
    double S = red[0], Q = red[1];
    double mu_d = S / tot;
    double var_d = Q / tot - mu_d*mu_d;
    if (var_d < 0.0) var_d = 0.0;
    mu  = (float)mu_d;
    inv = 1.0f / ((float)sqrt(var_d) + 1e-5f);
  }

  f32x4 acc[4][2];
  #pragma unroll
  for (int mt=0;mt<4;++mt)
    #pragma unroll
    for (int nt=0;nt<2;++nt) acc[mt][nt] = (f32x4){0.f,0.f,0.f,0.f};

  #pragma unroll
  for (int k0 = 0; k0 < K; k0 += 32){
    const int kb = k0 + quad*8;
    bf16x8 bf[2];
    #pragma unroll
    for (int nt=0;nt<2;++nt)
      bf[nt] = *(const bf16x8*)(Bt + (size_t)(col0 + nt*16 + l15)*K + kb);
    #pragma unroll
    for (int mt=0;mt<4;++mt){
      int r = rowBase + mt*16 + l15;
      if (r >= M) r = M-1;             // clamped load; store is guarded
      bf16x8 af;
      if (EXT){
        const float* ap = (const float*)Av + (size_t)r*K + kb;
        #pragma unroll
        for (int j=0;j<8;++j) ((unsigned short*)&af)[j] = f2bf(ap[j]);
      } else if (LNDROP){
        const unsigned short* ap = (const unsigned short*)Av + (size_t)r*K + kb;
        #pragma unroll
        for (int j=0;j<8;++j){
          int c = kb + j;
          float d = ln_drop(bfu(ap[j]), mu, inv, gam[c], bet[c], k0f, k1f,
                            (uint32_t)(r*K + c));
          ((unsigned short*)&af)[j] = f2bf(d);
        }
      } else {
        af = *(const bf16x8*)((const unsigned short*)Av + (size_t)r*K + kb);
      }
      #pragma unroll
      for (int nt=0;nt<2;++nt)
        acc[mt][nt] = __builtin_amdgcn_mfma_f32_16x16x32_bf16(af, bf[nt], acc[mt][nt], 0,0,0);
    }
  }

  #pragma unroll
  for (int mt=0;mt<4;++mt){
    #pragma unroll
    for (int nt=0;nt<2;++nt){
      int col = col0 + nt*16 + l15;
      float bb = 0.f;
      if (RELUBIAS) bb = bias[col];
      #pragma unroll
      for (int reg=0;reg<4;++reg){
        int row = rowBase + mt*16 + quad*4 + reg;
        if (row < M){
          float vv = acc[mt][nt][reg];
          if (RELUBIAS) vv = fmaxf(vv + bb, 0.f);
          C[(size_t)row*128 + col] = f2bf(vv);
        }
      }
    }
  }
}

// ---- gather + fused last-block reduce (R16) ----
__global__ __launch_bounds__(256) void gcn_gather(const unsigned short* __restrict__ t,
    const int* __restrict__ rowptr, const int2* __restrict__ csr2,
    const float* __restrict__ dinv, const float* __restrict__ bcw,
    unsigned short* __restrict__ v, double* __restrict__ part,
    int* __restrict__ counter, double* __restrict__ red, int N)
{
  int node = (int)((blockIdx.x*256u + threadIdx.x) >> 6);
  int lane = threadIdx.x & 63;
  const char* tl = (const char*)t + lane*4;
  float ls = 0.f, lss = 0.f;
  if (node < N){
    float dn = dinv[node];
    unsigned int tv = *(const unsigned int*)(tl + ((size_t)node << 8));
    float ax = __uint_as_float(tv<<16), ay = __uint_as_float(tv & 0xffff0000u);
    float dn2 = dn*dn;
    ax *= dn2; ay *= dn2;
    int e0 = rowptr[node], e1 = rowptr[node+1];
    int e = e0;
    for (; e + 8 <= e1; e += 8){
      int2 p[8];
      #pragma unroll
      for (int q=0;q<8;++q) p[q] = csr2[e+q];
      unsigned int rv[8];
      #pragma unroll
      for (int q=0;q<8;++q) rv[q] = *(const unsigned int*)(tl + (unsigned int)p[q].x);
      #pragma unroll
      for (int q=0;q<8;++q){
        float c = __int_as_float(p[q].y);
        ax = fmaf(__uint_as_float(rv[q]<<16),           c, ax);
        ay = fmaf(__uint_as_float(rv[q] & 0xffff0000u), c, ay);
      }
    }
    for (; e < e1; ++e){
      int2 p = csr2[e];
      float c = __int_as_float(p.y);
      unsigned int sv = *(const unsigned int*)(tl + (unsigned int)p.x);
      ax = fmaf(__uint_as_float(sv<<16),           c, ax);
      ay = fmaf(__uint_as_float(sv & 0xffff0000u), c, ay);
    }
    ax += bcw[2*lane]; ay += bcw[2*lane+1];
    unsigned int pk = (unsigned int)f2bf(ax) | ((unsigned int)f2bf(ay) << 16);
    *(unsigned int*)((char*)v + ((size_t)node << 8) + lane*4) = pk;
    ls  = ax + ay;
    lss = ax*ax + ay*ay;
  }
  for (int off=32; off; off>>=1){ ls += __shfl_down(ls, off); lss += __shfl_down(lss, off); }
  __shared__ float ssum[4], ssq[4];
  __shared__ int isLast;
  int wv = threadIdx.x >> 6;
  if (lane==0){ ssum[wv]=ls; ssq[wv]=lss; }
  __syncthreads();
  if (threadIdx.x==0){
    double ps = (double)(ssum[0]+ssum[1]+ssum[2]+ssum[3]);
    double pq = (double)(ssq[0]+ssq[1]+ssq[2]+ssq[3]);
    __hip_atomic_store(&part[2*blockIdx.x],   ps, __ATOMIC_RELAXED, __HIP_MEMORY_SCOPE_AGENT);
    __hip_atomic_store(&part[2*blockIdx.x+1], pq, __ATOMIC_RELAXED, __HIP_MEMORY_SCOPE_AGENT);
    int c = __hip_atomic_fetch_add(counter, 1, __ATOMIC_ACQ_REL, __HIP_MEMORY_SCOPE_AGENT);
    isLast = (c == (int)gridDim.x - 1);
  }
  __syncthreads();
  if (isLast){
    int nblocks = (int)gridDim.x;
    double s = 0.0, q = 0.0;
    for (int i = threadIdx.x; i < nblocks; i += 256){
      s += __hip_atomic_load(&part[2*i],   __ATOMIC_RELAXED, __HIP_MEMORY_SCOPE_AGENT);
      q += __hip_atomic_load(&part[2*i+1], __ATOMIC_RELAXED, __HIP_MEMORY_SCOPE_AGENT);
    }
    __shared__ double shs[256], shq[256];
    shs[threadIdx.x] = s; shq[threadIdx.x] = q; __syncthreads();
    for (int o=128;o;o>>=1){
      if (threadIdx.x<o){ shs[threadIdx.x]+=shs[threadIdx.x+o]; shq[threadIdx.x]+=shq[threadIdx.x+o]; }
      __syncthreads();
    }
    if (threadIdx.x==0){ red[0]=shs[0]; red[1]=shq[0]; }
  }
}

// -------- out = softmax( LNdrop(v) @ W_out + b_out ) -> f32 (LN fused, R16) --------
__global__ __launch_bounds__(256) void out_softmax(const unsigned short* __restrict__ v,
    const double* __restrict__ red, const float* __restrict__ gam, const float* __restrict__ bet,
    uint32_t k0f, uint32_t k1f,
    const float* __restrict__ Wo, const float* __restrict__ bo,
    float2* __restrict__ outv, int N, double tot)
{
  int node = (int)((blockIdx.x*256u + threadIdx.x) >> 6);
  int lane = threadIdx.x & 63;
  if (node >= N) return;
  double S = red[0], Q = red[1];
  double mu_d = S / tot;
  double var_d = Q / tot - mu_d*mu_d;
  if (var_d < 0.0) var_d = 0.0;
  float mu  = (float)mu_d;
  float inv = 1.0f / ((float)sqrt(var_d) + 1e-5f);

  unsigned int hv = ((const unsigned int*)(v + (size_t)node*H_DIM))[lane];
  int c0 = 2*lane, c1 = 2*lane+1;
  uint32_t jb = (uint32_t)(node*H_DIM);
  float h0 = ln_drop(bfu((unsigned short)(hv & 0xffffu)), mu, inv, gam[c0], bet[c0], k0f, k1f, jb + c0);
  float h1 = ln_drop(bfu((unsigned short)(hv >> 16)),     mu, inv, gam[c1], bet[c1], k0f, k1f, jb + c1);
  float4 wq = ((const float4*)Wo)[lane];
  float d0 = h0*wq.x + h1*wq.z;
  float d1 = h0*wq.y + h1*wq.w;
  for (int off=32; off; off>>=1){ d0 += __shfl_down(d0, off); d1 += __shfl_down(d1, off); }
  if (lane==0){
    d0 += bo[0]; d1 += bo[1];
    float m = fmaxf(d0, d1);
    float e0 = expf(d0 - m), e1 = expf(d1 - m);
    float s = e0 + e1;
    outv[node] = make_float2(e0/s, e1/s);
  }
}

// ---------------- launch ----------------
extern "C" void kernel_launch(void* const* d_in, const int* in_sizes, int n_in,
                              void* d_out, int out_size, void* d_ws, size_t ws_size,
                              hipStream_t stream) {
  (void)n_in; (void)out_size; (void)ws_size;
  const int N = in_sizes[0] / D_IN;     // x is [N, 64]
  const int E = in_sizes[1] / 2;        // edge_index is [2, E]
  const int total = N * H_DIM;
  const double tot = (double)total;

  const float* x    = (const float*)d_in[0];
  const int*   ei   = (const int*)d_in[1];
  const float* W_in = (const float*)d_in[2];
  const float* b_in = (const float*)d_in[3];
  const float* Wc   = (const float*)d_in[4];
  const float* bc   = (const float*)d_in[5];
  const float* gam  = (const float*)d_in[6];
  const float* bet  = (const float*)d_in[7];
  const float* W_o  = (const float*)d_in[8];
  const float* b_o  = (const float*)d_in[9];
  const int* src = ei;
  const int* dst = ei + E;
  char* ws = (char*)d_ws;

  const int nb = (N + 1023) >> 10;      // scan blocks
  const int nodeBlocks = (N + 3) / 4;   // 64 lanes per node
  const int zb = (N + 255) / 256;

  // runtime workspace layout, 256B-aligned slabs
  size_t o = 0;
  auto take = [&](size_t bytes)->char*{ char* p = ws + o; o = (o + bytes + 255) & ~(size_t)255; return p; };
  double* red    = (double*)take(4*sizeof(double));
  int*    ctrs   = (int*)   take(2*sizeof(int));
  double* part   = (double*)take((size_t)nodeBlocks*2*sizeof(double));
  float*  dinv   = (float*) take((size_t)N*4);
  int*    cnt    = (int*)   take((size_t)N*4);
  int*    rowptr = (int*)   take(((size_t)N+1)*4);
  int*    bsum   = (int*)   take((size_t)nb*4);
  int*    boff   = (int*)   take((size_t)nb*4);
  unsigned short* wt = (unsigned short*)take((size_t)WT_TOT*2);
  int2*   csr2   = (int2*)  take((size_t)E*8);
  int*    perm   = (int*)   take((size_t)E*4);
  unsigned short* actA = (unsigned short*)take((size_t)total*2);
  unsigned short* actB = (unsigned short*)take((size_t)total*2);

  // fold_in(key(1), i) = tf2x32(key=(0,1), counter=[0,i]) — verified
  uint32_t k00,k01,k10,k11;
  tf2x32(0u,1u,0u,0u,&k00,&k01);
  tf2x32(0u,1u,0u,1u,&k10,&k11);

  k_prep  <<<zb + (WT_TOT+255)/256, 256,0,stream>>>(cnt, zb, N, W_in, Wc, wt, ctrs);
  k_count <<<(E+255)/256,256,0,stream>>>(dst, cnt, perm, E);
  k_scan1 <<<nb,  256,0,stream>>>(cnt, bsum, N);
  k_scan2 <<<1,   128,0,stream>>>(bsum, boff, nb, rowptr, N);
  k_scan3 <<<nb,  256,0,stream>>>(cnt, boff, rowptr, dinv, N);
  k_fill  <<<(E+255)/256,256,0,stream>>>(src, dst, rowptr, perm, dinv, csr2, E);

  const int gemmBlocks = (N + 63) / 64;

  // A <- relu(x @ W_in + b_in)   [MFMA, f32 A]
  gemm_mfma<64,true,true,false><<<gemmBlocks,256,0,stream>>>(x, wt+WT_IN, b_in, actA, N,
      nullptr, nullptr, nullptr, 0u, 0u, tot);

  // layer 0: t0 = h_in @ Wc0 ; v0 = agg(t0)+bc0 (+stats -> red[0..1])
  gemm_mfma<128,false,false,false><<<gemmBlocks,256,0,stream>>>(actA, wt+WT_C0, nullptr, actB, N,
      nullptr, nullptr, nullptr, 0u, 0u, tot);
  gcn_gather<<<nodeBlocks,256,0,stream>>>(actB, rowptr, csr2, dinv, bc, actA, part, ctrs+0, red, N);

  // layer 1: t1 = LNdrop0(v0) @ Wc1  [LN fused into A-load] ; v1 = agg(t1)+bc1 (+stats -> red[2..3])
  gemm_mfma<128,false,false,true><<<gemmBlocks,256,0,stream>>>(actA, wt+WT_C1, nullptr, actB, N,
      red, gam, bet, k00, k01, tot);
  gcn_gather<<<nodeBlocks,256,0,stream>>>(actB, rowptr, csr2, dinv, bc + 128, actA, part, ctrs+1, red+2, N);

  // out: softmax( LNdrop1(v1) @ W_out + b_out )  [LN fused]
  out_softmax<<<nodeBlocks,256,0,stream>>>(actA, red+2, gam + 128, bet + 128, k10, k11,
      W_o, b_o, (float2*)d_out, N, tot);
}